// Round 2
// baseline (2250.294 us; speedup 1.0000x reference)
//
#include <hip/hip_runtime.h>

#define NQ 1032
#define NE 520
#define NO 512

// ---- output offsets, complex-interleaved mode (floats) ----
#define C_ETA 0
#define C_L1  1056768
#define C_G   5283840
#define C_B   7380992
#define C_F   142647296
#define C_PSI 151035904
#define C_TOTAL 151052288

// ---- output offsets, real-only mode (floats) ----
#define R_ETA 0
#define R_L1  528384
#define R_G   2641920
#define R_B   3690496
#define R_F   71323648
#define R_PSI 75517952

// ---- fp32 scratch pool (float offsets; in d_ws or carved from o_l1 region) ----
#define SL_PSI32 0
#define SL_THC32 9216
#define SL_THS32 142336
#define SL_BSEL  275456
#define SL_TOTALF 1332224   // floats (o_l1 region >= 2,113,536 floats even in real mode)

// ---- fp64 scratch pool (byte offsets; in d_ws or carved from o_b region) ----
#define SB_PSI64 0
#define SB_THC64 69632
#define SB_THS64 1130496
#define SB_CT    2191360
#define SB_A0    2262016
#define SB_B0    6592512
#define SB_B1    10856448
#define SB_INVD  15054848
#define SB_LT    15059008
#define SB_RZ    19851328
#define SB_TOTAL 24643648   // bytes (o_b region >= 270 MB even in real mode)

__device__ inline void tri_it(int e, int& i, int& t){
  int ii = (int)((sqrt(8.0*(double)e + 1.0) - 1.0) * 0.5);
  int base = (ii*(ii+1)) >> 1;
  while (base + ii + 1 <= e){ base += ii + 1; ++ii; }
  while (base > e){ base -= ii; --ii; }
  i = ii; t = e - base;
}

// psi interp + theta cos/sin tables + psi_mtx output
__global__ __launch_bounds__(256) void k_prep(const float* tf, const float* theta,
    float* psi32, double* psi64, double* thc64, double* ths64,
    float* thc32, float* ths32, float* o_psi, int cpx){
  int idx = blockIdx.x*256 + threadIdx.x;
  if (idx < 8192){
    int k = idx >> 10, p = idx & 1023;
    double x = 0.25*(double)p - 0.375;
    x = fmin(fmax(x, 0.0), 255.0);
    int x0 = (int)x;
    int x1 = min(x0+1, 255);
    double w = x - (double)x0;
    double v = (double)tf[k*256+x0]*(1.0-w) + (double)tf[k*256+x1]*w;
    psi64[k*1024+p] = v;
    float vf = (float)v;
    psi32[k*1024+p] = vf;
    if (cpx){ o_psi[idx*2+0] = vf; o_psi[idx*2+1] = 0.f; }
    else    { o_psi[idx] = vf; }
  } else {
    int j = idx - 8192;
    if (j < 129*1024){
      int n = j >> 10, p = j & 1023;
      double a = (double)(n-64)*(double)theta[p];
      double c = cos(a), s = sin(a);
      thc64[j] = c; ths64[j] = s;
      thc32[j] = (float)c; ths32[j] = (float)s;
    }
  }
}

// L1 output: self-contained; runs LAST (clobbers fp32 scratch if carved).
__global__ __launch_bounds__(256) void k_l1out(const float* tf, const float* theta,
    float* out_l1, int cpx){
  int row = blockIdx.x; int p = row & 1023; int bot = row >> 10;
  __shared__ float cc[129], ss[129], pp[8];
  int tid = threadIdx.x;
  float th = theta[p];
  if (tid < 129){
    float a = (float)(tid - 64) * th;
    cc[tid] = cosf(a); ss[tid] = sinf(a);
  }
  if (tid >= 192 && tid < 200){
    int k = tid - 192;
    float x = 0.25f*(float)p - 0.375f;
    x = fminf(fmaxf(x, 0.f), 255.f);
    int x0 = (int)x;
    int x1 = min(x0+1, 255);
    float w = x - (float)x0;
    pp[k] = tf[k*256+x0]*(1.f-w) + tf[k*256+x1]*w;
  }
  __syncthreads();
  for (int q = tid; q < NQ; q += 256){
    int n = q >> 3, k = q & 7;
    float sg = (bot && (n & 1)) ? -1.f : 1.f;
    float w = pp[k]*sg;
    if (cpx) ((float2*)out_l1)[(size_t)row*NQ + q] = make_float2(cc[n]*w, ss[n]*w);
    else     out_l1[(size_t)row*NQ + q] = cc[n]*w;
  }
}

// C[d][k][k'] = sum_p exp(i*2d*theta_p) psi_k psi_k'
__global__ __launch_bounds__(256) void k_ctab(const float* theta, const double* psi64, double2* C){
  int t = blockIdx.x; double dd = 2.0*(double)t;
  __shared__ double cs[1024], sn[1024];
  __shared__ double red[4][2];
  int tid = threadIdx.x;
  for (int p = tid; p < 1024; p += 256){ double a = dd*(double)theta[p]; cs[p] = cos(a); sn[p] = sin(a); }
  __syncthreads();
  int lane = tid & 63, wid = tid >> 6;
  for (int k = 0; k < 8; ++k) for (int k2 = k; k2 < 8; ++k2){
    double sr = 0, si = 0;
    for (int p = tid; p < 1024; p += 256){
      double w = psi64[k*1024+p]*psi64[k2*1024+p];
      sr += cs[p]*w; si += sn[p]*w;
    }
    for (int o = 32; o > 0; o >>= 1){ sr += __shfl_down(sr, o, 64); si += __shfl_down(si, o, 64); }
    if (lane == 0){ red[wid][0] = sr; red[wid][1] = si; }
    __syncthreads();
    if (tid == 0){
      double R = red[0][0]+red[1][0]+red[2][0]+red[3][0];
      double I = red[0][1]+red[1][1]+red[2][1]+red[3][1];
      C[t*64 + k*8 + k2] = make_double2(R, I);
      C[t*64 + k2*8 + k] = make_double2(R, I);
    }
    __syncthreads();
  }
}

// A0[(i,k),(j,k')] = 2*C[j-i][k][k'] (conj for j<i)
__global__ __launch_bounds__(256) void k_afill(const double2* C, double2* A){
  int idx = blockIdx.x*256 + threadIdx.x;
  if (idx >= NE*NE) return;
  int r = idx / NE, cix = idx - r*NE;
  int k = r & 7, i = r >> 3, j = cix >> 3, k2 = cix & 7;
  int dt = j - i;
  double2 v;
  if (dt >= 0){ v = C[dt*64 + k*8 + k2]; v.x *= 2.0; v.y *= 2.0; }
  else { v = C[(-dt)*64 + k*8 + k2]; v.x *= 2.0; v.y *= -2.0; }
  A[idx] = v;
}

// B = L1^H g via structure
__global__ __launch_bounds__(256) void k_bgemm(const float* g, const double* thc64, const double* ths64,
    const double* psi64, double2* B0, double2* B1){
  int n = blockIdx.x; int m0 = blockIdx.y * 128;
  int par = n & 1;
  __shared__ float u[64][129];
  __shared__ double cs[64], sn[64], ps[8][64];
  int tid = threadIdx.x;
  int k = tid >> 5, mg = tid & 31;
  double ar[4] = {0,0,0,0}, ai[4] = {0,0,0,0};
  for (int p0 = 0; p0 < 1024; p0 += 64){
    __syncthreads();
    if (tid < 64){ cs[tid] = thc64[n*1024 + p0 + tid]; sn[tid] = ths64[n*1024 + p0 + tid]; }
    for (int e = tid; e < 512; e += 256){ int kk = e >> 6, pp = e & 63; ps[kk][pp] = psi64[kk*1024 + p0 + pp]; }
    for (int e = tid; e < 2048; e += 256){
      int m = e >> 4, p4 = (e & 15) * 4;
      const float4 a = *(const float4*)(g + (size_t)(m0+m)*2048 + p0 + p4);
      const float4 b = *(const float4*)(g + (size_t)(m0+m)*2048 + 1024 + p0 + p4);
      float4 uu;
      if (par){ uu.x = a.x-b.x; uu.y = a.y-b.y; uu.z = a.z-b.z; uu.w = a.w-b.w; }
      else    { uu.x = a.x+b.x; uu.y = a.y+b.y; uu.z = a.z+b.z; uu.w = a.w+b.w; }
      u[p4+0][m] = uu.x; u[p4+1][m] = uu.y; u[p4+2][m] = uu.z; u[p4+3][m] = uu.w;
    }
    __syncthreads();
    for (int p = 0; p < 64; ++p){
      double w = ps[k][p];
      double wr = cs[p]*w, wi = sn[p]*w;
      #pragma unroll
      for (int j = 0; j < 4; ++j){
        double uu = (double)u[p][mg + 32*j];
        ar[j] += wr*uu; ai[j] -= wi*uu;
      }
    }
  }
  int hr = (n >> 1)*8 + k;
  double2* B = par ? B1 : B0;
  #pragma unroll
  for (int j = 0; j < 4; ++j) B[(size_t)hr*512 + m0 + mg + 32*j] = make_double2(ar[j], ai[j]);
}

// panel Cholesky 65x65 (packed lower triangle in LDS)
__global__ __launch_bounds__(256) void k_potrf(double2* A, double* invd, int j0){
  __shared__ double2 T[2145];
  int tid = threadIdx.x;
  for (int e = tid; e < 2145; e += 256){
    int i, t; tri_it(e, i, t);
    T[e] = A[(size_t)(j0+i)*NE + j0 + t];
  }
  __syncthreads();
  for (int j = 0; j < 65; ++j){
    double inv = 1.0 / T[(j*(j+1))/2 + j].x;
    int i = j + 1 + (tid & 63);
    if (i < 65){
      double2 lij = T[(i*(i+1))/2 + j];
      for (int t = j+1+(tid>>6); t <= i; t += 4){
        double2 ltj = T[(t*(t+1))/2 + j];
        double2 a = T[(i*(i+1))/2 + t];
        a.x -= (lij.x*ltj.x + lij.y*ltj.y)*inv;
        a.y -= (lij.y*ltj.x - lij.x*ltj.y)*inv;
        T[(i*(i+1))/2 + t] = a;
      }
    }
    __syncthreads();
  }
  for (int e = tid; e < 2145; e += 256){
    int i, t; tri_it(e, i, t);
    double dinv = 1.0 / sqrt(T[(t*(t+1))/2 + t].x);
    double2 v = T[e]; v.x *= dinv; v.y *= dinv;
    A[(size_t)(j0+i)*NE + j0 + t] = v;
    if (i == t) invd[j0+i] = dinv;
  }
}

// TRSM: L21 = A21 * inv(L11)^H  (L11 staged column-major in LDS)
__global__ __launch_bounds__(256) void k_trsm(double2* A, const double* invd, int j0){
  __shared__ double2 Lp[65*65];   // Lp[c*65 + i] = L11[i][c]
  __shared__ double ivp[65];
  int tid = threadIdx.x;
  for (int e = tid; e < 65*65; e += 256){
    int i = e / 65, c = e - i*65;
    Lp[c*65 + i] = A[(size_t)(j0+i)*NE + j0 + c];
  }
  if (tid < 65) ivp[tid] = invd[j0 + tid];
  __syncthreads();
  int lane = tid & 63, wid = tid >> 6;
  int rg = j0 + 65 + blockIdx.x*4 + wid;
  if (rg >= NE) return;
  double2 a0 = A[(size_t)rg*NE + j0 + lane];
  double2 a64 = (lane == 0) ? A[(size_t)rg*NE + j0 + 64] : make_double2(0,0);
  for (int c = 0; c < 65; ++c){
    double xr, xi;
    if (c < 64){ xr = __shfl(a0.x, c, 64); xi = __shfl(a0.y, c, 64); }
    else { xr = __shfl(a64.x, 0, 64); xi = __shfl(a64.y, 0, 64); }
    double iv = ivp[c];
    xr *= iv; xi *= iv;
    if (c < 64){ if (lane == c){ a0.x = xr; a0.y = xi; } }
    else if (lane == 0){ a64.x = xr; a64.y = xi; }
    if (lane > c){
      double2 l = Lp[c*65 + lane];
      a0.x -= xr*l.x + xi*l.y; a0.y -= xi*l.x - xr*l.y;
    }
    if (lane == 0 && c < 64){
      double2 l = Lp[c*65 + 64];
      a64.x -= xr*l.x + xi*l.y; a64.y -= xi*l.x - xr*l.y;
    }
  }
  A[(size_t)rg*NE + j0 + lane] = a0;
  if (lane == 0) A[(size_t)rg*NE + j0 + 64] = a64;
}

// SYRK: A22 -= L21 L21^H (lower only)
__global__ __launch_bounds__(256) void k_syrk(double2* A, int j0){
  if (blockIdx.y > blockIdx.x) return;
  int j1 = j0 + 65;
  int i0 = j1 + blockIdx.x*32, t0 = j1 + blockIdx.y*32;
  __shared__ double2 Li[32][17];
  __shared__ double2 Lt[32][17];
  int tid = threadIdx.x;
  int oi = tid >> 3, tj = (tid & 7)*4;
  double2 acc[4] = {make_double2(0,0),make_double2(0,0),make_double2(0,0),make_double2(0,0)};
  for (int c0 = 0; c0 < 65; c0 += 16){
    int cw = min(16, 65 - c0);
    __syncthreads();
    for (int e = tid; e < 512; e += 256){
      int r = e >> 4, c = e & 15;
      double2 zi = make_double2(0,0), zt = zi;
      if (c < cw){
        if (i0 + r < NE) zi = A[(size_t)(i0+r)*NE + j0 + c0 + c];
        if (t0 + r < NE) zt = A[(size_t)(t0+r)*NE + j0 + c0 + c];
      }
      Li[r][c] = zi; Lt[r][c] = zt;
    }
    __syncthreads();
    for (int c = 0; c < cw; ++c){
      double2 li = Li[oi][c];
      #pragma unroll
      for (int j = 0; j < 4; ++j){
        double2 lt = Lt[tj+j][c];
        acc[j].x += li.x*lt.x + li.y*lt.y;
        acc[j].y += li.y*lt.x - li.x*lt.y;
      }
    }
  }
  int gi = i0 + oi;
  if (gi < NE){
    #pragma unroll
    for (int j = 0; j < 4; ++j){
      int gt = t0 + tj + j;
      if (gt < NE && gt <= gi){
        double2 v = A[(size_t)gi*NE + gt];
        v.x -= acc[j].x; v.y -= acc[j].y;
        A[(size_t)gi*NE + gt] = v;
      }
    }
  }
}

// LT[c*576+t] = A[t*NE+c] for t>c (t<520), else 0.  (column-major L, zero-padded)
__global__ __launch_bounds__(256) void k_tr(const double2* A, double2* LT){
  __shared__ double2 tl[32][33];
  int bc = blockIdx.x*32;   // column (c) tile base
  int bt = blockIdx.y*32;   // row (t) tile base
  int lx = threadIdx.x & 31, ly = threadIdx.x >> 5;   // 8 rows per pass
  #pragma unroll
  for (int rr = 0; rr < 32; rr += 8){
    int t = bt + ly + rr, c = bc + lx;
    double2 v = make_double2(0,0);
    if (t < NE && c < NE && t > c) v = A[(size_t)t*NE + c];
    tl[ly+rr][lx] = v;
  }
  __syncthreads();
  #pragma unroll
  for (int rr = 0; rr < 32; rr += 8){
    int c = bc + ly + rr, t = bt + lx;
    if (c < NE) LT[(size_t)c*576 + t] = tl[lx][ly+rr];
  }
}

// RZ[c*576+t] = A[c*NE+t] for t<c, else 0.   (rows of L, zero-padded)
__global__ __launch_bounds__(256) void k_rz(const double2* A, double2* RZ){
  int idx = blockIdx.x*256 + threadIdx.x;   // over 520*576
  if (idx >= NE*576) return;
  int c = idx / 576, t = idx - c*576;
  double2 v = (t < c) ? A[(size_t)c*NE + t] : make_double2(0,0);
  RZ[idx] = v;
}

// ---- solve: per-panel-specialized chunk processors (RR = panel index) ----
template<int RR>
__device__ __forceinline__ void fwd4(double2* y, const double2* Lsc, const double* ivc, int cb, int lane){
  constexpr int NR64 = (9 - RR)*64;
  #pragma unroll
  for (int cc = 0; cc < 4; ++cc){
    int la = (cb + cc) & 63;
    double iv = ivc[cc];
    double xr = __shfl(y[RR].x, la, 64)*iv;
    double xi = __shfl(y[RR].y, la, 64)*iv;
    if (lane == la){ y[RR].x = xr; y[RR].y = xi; }
    #pragma unroll
    for (int r = RR; r < 9; ++r){
      double2 l = Lsc[cc*NR64 + (r-RR)*64 + lane];  // zero for t<=c, t>=520
      y[r].x -= l.x*xr - l.y*xi;
      y[r].y -= l.x*xi + l.y*xr;
    }
  }
}

template<int RR>
__device__ __forceinline__ void bwd4(double2* y, const double2* Lsc, const double* ivc, int cb, int lane){
  constexpr int NR64 = (RR + 1)*64;
  #pragma unroll
  for (int cc = 3; cc >= 0; --cc){
    int la = (cb + cc) & 63;
    double iv = ivc[cc];
    double xr = __shfl(y[RR].x, la, 64)*iv;
    double xi = __shfl(y[RR].y, la, 64)*iv;
    if (lane == la){ y[RR].x = xr; y[RR].y = xi; }
    #pragma unroll
    for (int r = 0; r <= RR; ++r){
      double2 l = Lsc[cc*NR64 + r*64 + lane];       // zero for t>=c
      y[r].x -= l.x*xr + l.y*xi;
      y[r].y -= l.x*xi - l.y*xr;
    }
  }
}

// forward+backward substitution; 256 blocks x 4 waves, 1 RHS per wave.
// L panels double-buffered in LDS (4 cols/chunk, only nonzero row-blocks),
// loads issued post-barrier and covered by chunk processing.
__global__ __launch_bounds__(256,1) void k_solve(const double2* __restrict__ LT, const double2* __restrict__ RZ,
                                                 const double* __restrict__ invd,
                                                 double2* B0, double2* B1){
  __shared__ double2 Ls[2][4*576];
  __shared__ double ivb[2][4];
  int tid = threadIdx.x, lane = tid & 63, z = tid >> 6;
  int w = blockIdx.x*4 + z;                 // 0..1023
  int sys = (w >= 512) ? 1 : 0;             // uniform per block
  int c0 = sys ? (w - 512) : w;
  int n = sys ? NO : NE;
  double2* B = sys ? B1 : B0;
  double2 y[9];
  #pragma unroll
  for (int r = 0; r < 9; ++r){
    int t = r*64 + lane;
    y[r] = (t < n) ? B[(size_t)t*512 + c0] : make_double2(0,0);
  }
  int nch = n >> 2;                         // 130 or 128 (exact)
  double2 stg[9]; double ivs = 0;

  // ---------- forward ----------
  {
    size_t ga = (size_t)z*576 + lane;       // chunk 0: RR=0, nr=9
    #pragma unroll
    for (int i = 0; i < 9; ++i) stg[i] = LT[ga + i*64];
    if (tid < 4) ivs = invd[tid];
    #pragma unroll
    for (int i = 0; i < 9; ++i) Ls[0][z*576 + i*64 + lane] = stg[i];
    if (tid < 4) ivb[0][tid] = ivs;
  }
  for (int k = 0; k < nch; ++k){
    int cur = k & 1;
    __syncthreads();                        // Ls[cur] ready
    int rrn = (k+1) >> 4;
    if (k+1 < nch){
      int nr = 9 - rrn;
      size_t ga = (size_t)((k+1)*4 + z)*576 + rrn*64 + lane;
      #pragma unroll
      for (int i = 0; i < 9; ++i) if (i < nr) stg[i] = LT[ga + i*64];
      if (tid < 4) ivs = invd[(k+1)*4 + tid];
    }
    int cb = k*4;
    const double2* Lsc = &Ls[cur][0];
    const double* ivc = &ivb[cur][0];
    switch (k >> 4){
      case 0: fwd4<0>(y, Lsc, ivc, cb, lane); break;
      case 1: fwd4<1>(y, Lsc, ivc, cb, lane); break;
      case 2: fwd4<2>(y, Lsc, ivc, cb, lane); break;
      case 3: fwd4<3>(y, Lsc, ivc, cb, lane); break;
      case 4: fwd4<4>(y, Lsc, ivc, cb, lane); break;
      case 5: fwd4<5>(y, Lsc, ivc, cb, lane); break;
      case 6: fwd4<6>(y, Lsc, ivc, cb, lane); break;
      case 7: fwd4<7>(y, Lsc, ivc, cb, lane); break;
      default: fwd4<8>(y, Lsc, ivc, cb, lane); break;
    }
    if (k+1 < nch){
      int nr = 9 - rrn, nr64 = (9 - rrn)*64;
      #pragma unroll
      for (int i = 0; i < 9; ++i) if (i < nr) Ls[cur^1][z*nr64 + i*64 + lane] = stg[i];
      if (tid < 4) ivb[cur^1][tid] = ivs;
    }
  }

  // ---------- backward ----------
  {
    int kb = nch - 1;
    int nr = (kb >> 4) + 1, nr64 = nr*64;
    size_t ga = (size_t)(kb*4 + z)*576 + lane;
    #pragma unroll
    for (int i = 0; i < 9; ++i) if (i < nr) stg[i] = RZ[ga + i*64];
    if (tid < 4) ivs = invd[kb*4 + tid];
    // safe: all waves passed fwd iter nch-1's barrier; Ls[0] last read in fwd iter nch-2
    #pragma unroll
    for (int i = 0; i < 9; ++i) if (i < nr) Ls[0][z*nr64 + i*64 + lane] = stg[i];
    if (tid < 4) ivb[0][tid] = ivs;
  }
  for (int k = nch-1; k >= 0; --k){
    int cur = (nch-1 - k) & 1;
    __syncthreads();                        // Ls[cur] ready
    if (k > 0){
      int nr = ((k-1) >> 4) + 1;
      size_t ga = (size_t)((k-1)*4 + z)*576 + lane;
      #pragma unroll
      for (int i = 0; i < 9; ++i) if (i < nr) stg[i] = RZ[ga + i*64];
      if (tid < 4) ivs = invd[(k-1)*4 + tid];
    }
    int cb = k*4;
    const double2* Lsc = &Ls[cur][0];
    const double* ivc = &ivb[cur][0];
    switch (k >> 4){
      case 0: bwd4<0>(y, Lsc, ivc, cb, lane); break;
      case 1: bwd4<1>(y, Lsc, ivc, cb, lane); break;
      case 2: bwd4<2>(y, Lsc, ivc, cb, lane); break;
      case 3: bwd4<3>(y, Lsc, ivc, cb, lane); break;
      case 4: bwd4<4>(y, Lsc, ivc, cb, lane); break;
      case 5: bwd4<5>(y, Lsc, ivc, cb, lane); break;
      case 6: bwd4<6>(y, Lsc, ivc, cb, lane); break;
      case 7: bwd4<7>(y, Lsc, ivc, cb, lane); break;
      default: bwd4<8>(y, Lsc, ivc, cb, lane); break;
    }
    if (k > 0){
      int nr = ((k-1) >> 4) + 1, nr64 = nr*64;
      #pragma unroll
      for (int i = 0; i < 9; ++i) if (i < nr) Ls[cur^1][z*nr64 + i*64 + lane] = stg[i];
      if (tid < 4) ivb[cur^1][tid] = ivs;
    }
  }

  #pragma unroll
  for (int r = 0; r < 9; ++r){
    int t = r*64 + lane;
    if (t < n) B[(size_t)t*512 + c0] = y[r];
  }
}

// eta output (interleave even/odd systems, f64 -> f32)
__global__ __launch_bounds__(256) void k_eta(const double2* B0, const double2* B1,
                                             float* out_eta, int cpx){
  int idx = blockIdx.x*256 + threadIdx.x;
  if (idx >= NQ*512) return;
  int q = idx >> 9;
  int m = idx & 511;
  int n = q >> 3, k = q & 7;
  const double2* B = (n & 1) ? B1 : B0;
  int hr = (n >> 1)*8 + k;
  double2 v = B[(size_t)hr*512 + m];
  if (cpx) ((float2*)out_eta)[idx] = make_float2((float)v.x, (float)v.y);
  else     out_eta[idx] = (float)v.x;
}

// fused: b output + g_est output + bsel extraction (BSEL scratch stays complex)
__global__ __launch_bounds__(256) void k_gestb(const double2* B0, const double2* B1,
    const float* psi32, const float* thc32, const float* ths32,
    float* out_b, float* out_g, float2* BSEL, int cpx){
  int m = blockIdx.x; int p = blockIdx.y*256 + threadIdx.x;
  __shared__ float4 eL4[516];
  float2* eL2 = (float2*)eL4;
  for (int e = threadIdx.x; e < NQ; e += 256){
    int n = e >> 3, k = e & 7;
    const double2* B = (n & 1) ? B1 : B0;
    double2 v = B[(size_t)((n >> 1)*8 + k)*512 + m];
    eL2[e] = make_float2((float)v.x, (float)v.y);
  }
  __syncthreads();
  float pr[8];
  #pragma unroll
  for (int k = 0; k < 8; ++k) pr[k] = psi32[k*1024+p];
  float aEx=0, aEy=0, aOx=0, aOy=0;
  size_t bbase = (size_t)m*129*1024 + p;
  for (int n = 0; n < 129; ++n){
    float c = thc32[n*1024+p], s = ths32[n*1024+p];
    float4 e0 = eL4[n*4+0], e1 = eL4[n*4+1], e2 = eL4[n*4+2], e3 = eL4[n*4+3];
    float br = e0.x*pr[0] + e0.z*pr[1] + e1.x*pr[2] + e1.z*pr[3]
             + e2.x*pr[4] + e2.z*pr[5] + e3.x*pr[6] + e3.z*pr[7];
    float bi = e0.y*pr[0] + e0.w*pr[1] + e1.y*pr[2] + e1.w*pr[3]
             + e2.y*pr[4] + e2.w*pr[5] + e3.y*pr[6] + e3.w*pr[7];
    if (cpx) ((float2*)out_b)[bbase + (size_t)n*1024] = make_float2(br, bi);
    else     out_b[bbase + (size_t)n*1024] = br;
    if ((p & 127) == 0) BSEL[(size_t)m*NQ + n*8 + (p >> 7)] = make_float2(br, bi);
    float tr = c*br - s*bi, ti = c*bi + s*br;
    if (n & 1){ aOx += tr; aOy += ti; } else { aEx += tr; aEy += ti; }
  }
  if (cpx){
    ((float2*)out_g)[(size_t)m*2048 + p]        = make_float2(aEx+aOx, aEy+aOy);
    ((float2*)out_g)[(size_t)m*2048 + p + 1024] = make_float2(aEx-aOx, aEy-aOy);
  } else {
    out_g[(size_t)m*2048 + p]        = aEx+aOx;
    out_g[(size_t)m*2048 + p + 1024] = aEx-aOx;
  }
}

// f_pol_est_s output
__global__ __launch_bounds__(256) void k_fpol(const float2* BSEL, const float* thc32,
    const float* ths32, float* out_f, int cpx){
  int m = blockIdx.x; int p = blockIdx.y*256 + threadIdx.x;
  __shared__ float4 bs4[516];
  float2* bs2 = (float2*)bs4;
  for (int e = threadIdx.x; e < NQ; e += 256) bs2[e] = BSEL[(size_t)m*NQ + e];
  __syncthreads();
  float ar[8] = {0,0,0,0,0,0,0,0}, ai[8] = {0,0,0,0,0,0,0,0};
  for (int n = 0; n < 129; ++n){
    float c = thc32[n*1024+p], s = ths32[n*1024+p];
    #pragma unroll
    for (int jj = 0; jj < 4; ++jj){
      float4 v = bs4[n*4+jj];
      ar[2*jj]   += c*v.x - s*v.y;  ai[2*jj]   += c*v.y + s*v.x;
      ar[2*jj+1] += c*v.z - s*v.w;  ai[2*jj+1] += c*v.w + s*v.z;
    }
  }
  if (cpx){
    float4* o = (float4*)(out_f + ((size_t)m*1024 + p)*16);
    o[0] = make_float4(ar[0],ai[0],ar[1],ai[1]);
    o[1] = make_float4(ar[2],ai[2],ar[3],ai[3]);
    o[2] = make_float4(ar[4],ai[4],ar[5],ai[5]);
    o[3] = make_float4(ar[6],ai[6],ar[7],ai[7]);
  } else {
    float4* o = (float4*)(out_f + ((size_t)m*1024 + p)*8);
    o[0] = make_float4(ar[0],ar[1],ar[2],ar[3]);
    o[1] = make_float4(ar[4],ar[5],ar[6],ar[7]);
  }
}

extern "C" void kernel_launch(void* const* d_in, const int* in_sizes, int n_in,
                              void* d_out, int out_size, void* d_ws, size_t ws_size,
                              hipStream_t stream){
  const float* g     = (const float*)d_in[0];
  const float* tf    = (const float*)d_in[1];
  const float* theta = (const float*)d_in[2];
  float* out = (float*)d_out;

  int cpx = (out_size >= C_TOTAL) ? 1 : 0;
  float* o_eta = out + (cpx ? C_ETA : R_ETA);
  float* o_l1  = out + (cpx ? C_L1  : R_L1);
  float* o_g   = out + (cpx ? C_G   : R_G);
  float* o_b   = out + (cpx ? C_B   : R_B);
  float* o_f   = out + (cpx ? C_F   : R_F);
  float* o_psi = out + (cpx ? C_PSI : R_PSI);

  // scratch pools: prefer d_ws when large enough, else carve from late-written outputs
  size_t need = (size_t)SB_TOTAL + (size_t)SL_TOTALF*4 + 4096;
  char*  sb;     // fp64 pool base
  float* sl;     // fp32 pool base
  if (ws_size >= need){
    sb = (char*)d_ws;
    sl = (float*)((char*)d_ws + SB_TOTAL);
  } else {
    sb = (char*)o_b;   // o_b region: >=270 MB (real) / 541 MB (cpx), dead until k_gestb
    sl = o_l1;         // o_l1 region: >=2.1M floats, dead until k_l1out (runs last)
  }
  float*   psi32 = sl + SL_PSI32;
  float*   thc32 = sl + SL_THC32;
  float*   ths32 = sl + SL_THS32;
  float2*  BSEL  = (float2*)(sl + SL_BSEL);
  double*  psi64 = (double*)(sb + SB_PSI64);
  double*  thc64 = (double*)(sb + SB_THC64);
  double*  ths64 = (double*)(sb + SB_THS64);
  double2* Ct    = (double2*)(sb + SB_CT);
  double2* A0    = (double2*)(sb + SB_A0);
  double2* B0    = (double2*)(sb + SB_B0);
  double2* B1    = (double2*)(sb + SB_B1);
  double*  INVD  = (double*)(sb + SB_INVD);
  double2* LT    = (double2*)(sb + SB_LT);
  double2* RZ    = (double2*)(sb + SB_RZ);

  k_prep <<<548, 256, 0, stream>>>(tf, theta, psi32, psi64, thc64, ths64, thc32, ths32, o_psi, cpx);
  k_ctab <<<65, 256, 0, stream>>>(theta, psi64, Ct);
  k_afill<<<1057, 256, 0, stream>>>(Ct, A0);
  k_bgemm<<<dim3(129,4), 256, 0, stream>>>(g, thc64, ths64, psi64, B0, B1);
  for (int s = 0; s < 8; ++s){
    k_potrf<<<1, 256, 0, stream>>>(A0, INVD, s*65);
    int rem = NE - 65*(s+1);
    if (rem > 0){
      k_trsm<<<(rem+3)/4, 256, 0, stream>>>(A0, INVD, s*65);
      int nt = (rem+31)/32;
      k_syrk<<<dim3(nt,nt), 256, 0, stream>>>(A0, s*65);
    }
  }
  k_tr   <<<dim3(17,18), 256, 0, stream>>>(A0, LT);
  k_rz   <<<(NE*576 + 255)/256, 256, 0, stream>>>(A0, RZ);
  k_solve<<<256, 256, 0, stream>>>(LT, RZ, INVD, B0, B1);
  k_eta  <<<2064, 256, 0, stream>>>(B0, B1, o_eta, cpx);
  k_gestb<<<dim3(512,4), 256, 0, stream>>>(B0, B1, psi32, thc32, ths32, o_b, o_g, BSEL, cpx);
  k_fpol <<<dim3(512,4), 256, 0, stream>>>(BSEL, thc32, ths32, o_f, cpx);
  k_l1out<<<2048, 256, 0, stream>>>(tf, theta, o_l1, cpx);
}

// Round 3
// 1676.716 us; speedup vs baseline: 1.3421x; 1.3421x over previous
//
#include <hip/hip_runtime.h>

#define NQ 1032
#define NE 520
#define NO 512

// ---- output offsets, complex-interleaved mode (floats) ----
#define C_ETA 0
#define C_L1  1056768
#define C_G   5283840
#define C_B   7380992
#define C_F   142647296
#define C_PSI 151035904
#define C_TOTAL 151052288

// ---- output offsets, real-only mode (floats) ----
#define R_ETA 0
#define R_L1  528384
#define R_G   2641920
#define R_B   3690496
#define R_F   71323648
#define R_PSI 75517952

// ---- fp32 scratch pool (float offsets; in d_ws or carved from o_l1 region) ----
#define SL_PSI32 0
#define SL_THC32 9216
#define SL_THS32 142336
#define SL_BSEL  275456
#define SL_TOTALF 1332224   // floats (o_l1 region >= 2,113,536 floats even in real mode)

// ---- fp64 scratch pool (byte offsets; in d_ws or carved from o_b region) ----
#define SB_PSI64 0
#define SB_THC64 69632
#define SB_THS64 1130496
#define SB_CT    2191360
#define SB_A0    2262016
#define SB_B0    6592512
#define SB_B1    10856448
#define SB_INVD  15054848
#define SB_LT    15059008
#define SB_RZ    19851328
#define SB_TOTAL 24643648   // bytes (o_b region >= 270 MB even in real mode)

__device__ inline void tri_it(int e, int& i, int& t){
  int ii = (int)((sqrt(8.0*(double)e + 1.0) - 1.0) * 0.5);
  int base = (ii*(ii+1)) >> 1;
  while (base + ii + 1 <= e){ base += ii + 1; ++ii; }
  while (base > e){ base -= ii; --ii; }
  i = ii; t = e - base;
}

// psi interp + theta cos/sin tables + psi_mtx output
__global__ __launch_bounds__(256) void k_prep(const float* tf, const float* theta,
    float* psi32, double* psi64, double* thc64, double* ths64,
    float* thc32, float* ths32, float* o_psi, int cpx){
  int idx = blockIdx.x*256 + threadIdx.x;
  if (idx < 8192){
    int k = idx >> 10, p = idx & 1023;
    double x = 0.25*(double)p - 0.375;
    x = fmin(fmax(x, 0.0), 255.0);
    int x0 = (int)x;
    int x1 = min(x0+1, 255);
    double w = x - (double)x0;
    double v = (double)tf[k*256+x0]*(1.0-w) + (double)tf[k*256+x1]*w;
    psi64[k*1024+p] = v;
    float vf = (float)v;
    psi32[k*1024+p] = vf;
    if (cpx){ o_psi[idx*2+0] = vf; o_psi[idx*2+1] = 0.f; }
    else    { o_psi[idx] = vf; }
  } else {
    int j = idx - 8192;
    if (j < 129*1024){
      int n = j >> 10, p = j & 1023;
      double a = (double)(n-64)*(double)theta[p];
      double c = cos(a), s = sin(a);
      thc64[j] = c; ths64[j] = s;
      thc32[j] = (float)c; ths32[j] = (float)s;
    }
  }
}

// L1 output: self-contained; runs LAST (clobbers fp32 scratch if carved).
__global__ __launch_bounds__(256) void k_l1out(const float* tf, const float* theta,
    float* out_l1, int cpx){
  int row = blockIdx.x; int p = row & 1023; int bot = row >> 10;
  __shared__ float cc[129], ss[129], pp[8];
  int tid = threadIdx.x;
  float th = theta[p];
  if (tid < 129){
    float a = (float)(tid - 64) * th;
    cc[tid] = cosf(a); ss[tid] = sinf(a);
  }
  if (tid >= 192 && tid < 200){
    int k = tid - 192;
    float x = 0.25f*(float)p - 0.375f;
    x = fminf(fmaxf(x, 0.f), 255.f);
    int x0 = (int)x;
    int x1 = min(x0+1, 255);
    float w = x - (float)x0;
    pp[k] = tf[k*256+x0]*(1.f-w) + tf[k*256+x1]*w;
  }
  __syncthreads();
  for (int q = tid; q < NQ; q += 256){
    int n = q >> 3, k = q & 7;
    float sg = (bot && (n & 1)) ? -1.f : 1.f;
    float w = pp[k]*sg;
    if (cpx) ((float2*)out_l1)[(size_t)row*NQ + q] = make_float2(cc[n]*w, ss[n]*w);
    else     out_l1[(size_t)row*NQ + q] = cc[n]*w;
  }
}

// C[d][k][k'] = sum_p exp(i*2d*theta_p) psi_k psi_k'
__global__ __launch_bounds__(256) void k_ctab(const float* theta, const double* psi64, double2* C){
  int t = blockIdx.x; double dd = 2.0*(double)t;
  __shared__ double cs[1024], sn[1024];
  __shared__ double red[4][2];
  int tid = threadIdx.x;
  for (int p = tid; p < 1024; p += 256){ double a = dd*(double)theta[p]; cs[p] = cos(a); sn[p] = sin(a); }
  __syncthreads();
  int lane = tid & 63, wid = tid >> 6;
  for (int k = 0; k < 8; ++k) for (int k2 = k; k2 < 8; ++k2){
    double sr = 0, si = 0;
    for (int p = tid; p < 1024; p += 256){
      double w = psi64[k*1024+p]*psi64[k2*1024+p];
      sr += cs[p]*w; si += sn[p]*w;
    }
    for (int o = 32; o > 0; o >>= 1){ sr += __shfl_down(sr, o, 64); si += __shfl_down(si, o, 64); }
    if (lane == 0){ red[wid][0] = sr; red[wid][1] = si; }
    __syncthreads();
    if (tid == 0){
      double R = red[0][0]+red[1][0]+red[2][0]+red[3][0];
      double I = red[0][1]+red[1][1]+red[2][1]+red[3][1];
      C[t*64 + k*8 + k2] = make_double2(R, I);
      C[t*64 + k2*8 + k] = make_double2(R, I);
    }
    __syncthreads();
  }
}

// A0[(i,k),(j,k')] = 2*C[j-i][k][k'] (conj for j<i)
__global__ __launch_bounds__(256) void k_afill(const double2* C, double2* A){
  int idx = blockIdx.x*256 + threadIdx.x;
  if (idx >= NE*NE) return;
  int r = idx / NE, cix = idx - r*NE;
  int k = r & 7, i = r >> 3, j = cix >> 3, k2 = cix & 7;
  int dt = j - i;
  double2 v;
  if (dt >= 0){ v = C[dt*64 + k*8 + k2]; v.x *= 2.0; v.y *= 2.0; }
  else { v = C[(-dt)*64 + k*8 + k2]; v.x *= 2.0; v.y *= -2.0; }
  A[idx] = v;
}

// B = L1^H g via structure
__global__ __launch_bounds__(256) void k_bgemm(const float* g, const double* thc64, const double* ths64,
    const double* psi64, double2* B0, double2* B1){
  int n = blockIdx.x; int m0 = blockIdx.y * 128;
  int par = n & 1;
  __shared__ float u[64][129];
  __shared__ double cs[64], sn[64], ps[8][64];
  int tid = threadIdx.x;
  int k = tid >> 5, mg = tid & 31;
  double ar[4] = {0,0,0,0}, ai[4] = {0,0,0,0};
  for (int p0 = 0; p0 < 1024; p0 += 64){
    __syncthreads();
    if (tid < 64){ cs[tid] = thc64[n*1024 + p0 + tid]; sn[tid] = ths64[n*1024 + p0 + tid]; }
    for (int e = tid; e < 512; e += 256){ int kk = e >> 6, pp = e & 63; ps[kk][pp] = psi64[kk*1024 + p0 + pp]; }
    for (int e = tid; e < 2048; e += 256){
      int m = e >> 4, p4 = (e & 15) * 4;
      const float4 a = *(const float4*)(g + (size_t)(m0+m)*2048 + p0 + p4);
      const float4 b = *(const float4*)(g + (size_t)(m0+m)*2048 + 1024 + p0 + p4);
      float4 uu;
      if (par){ uu.x = a.x-b.x; uu.y = a.y-b.y; uu.z = a.z-b.z; uu.w = a.w-b.w; }
      else    { uu.x = a.x+b.x; uu.y = a.y+b.y; uu.z = a.z+b.z; uu.w = a.w+b.w; }
      u[p4+0][m] = uu.x; u[p4+1][m] = uu.y; u[p4+2][m] = uu.z; u[p4+3][m] = uu.w;
    }
    __syncthreads();
    for (int p = 0; p < 64; ++p){
      double w = ps[k][p];
      double wr = cs[p]*w, wi = sn[p]*w;
      #pragma unroll
      for (int j = 0; j < 4; ++j){
        double uu = (double)u[p][mg + 32*j];
        ar[j] += wr*uu; ai[j] -= wi*uu;
      }
    }
  }
  int hr = (n >> 1)*8 + k;
  double2* B = par ? B1 : B0;
  #pragma unroll
  for (int j = 0; j < 4; ++j) B[(size_t)hr*512 + m0 + mg + 32*j] = make_double2(ar[j], ai[j]);
}

// panel Cholesky 65x65 (packed lower triangle in LDS)
__global__ __launch_bounds__(256) void k_potrf(double2* A, double* invd, int j0){
  __shared__ double2 T[2145];
  int tid = threadIdx.x;
  for (int e = tid; e < 2145; e += 256){
    int i, t; tri_it(e, i, t);
    T[e] = A[(size_t)(j0+i)*NE + j0 + t];
  }
  __syncthreads();
  for (int j = 0; j < 65; ++j){
    double inv = 1.0 / T[(j*(j+1))/2 + j].x;
    int i = j + 1 + (tid & 63);
    if (i < 65){
      double2 lij = T[(i*(i+1))/2 + j];
      for (int t = j+1+(tid>>6); t <= i; t += 4){
        double2 ltj = T[(t*(t+1))/2 + j];
        double2 a = T[(i*(i+1))/2 + t];
        a.x -= (lij.x*ltj.x + lij.y*ltj.y)*inv;
        a.y -= (lij.y*ltj.x - lij.x*ltj.y)*inv;
        T[(i*(i+1))/2 + t] = a;
      }
    }
    __syncthreads();
  }
  for (int e = tid; e < 2145; e += 256){
    int i, t; tri_it(e, i, t);
    double dinv = 1.0 / sqrt(T[(t*(t+1))/2 + t].x);
    double2 v = T[e]; v.x *= dinv; v.y *= dinv;
    A[(size_t)(j0+i)*NE + j0 + t] = v;
    if (i == t) invd[j0+i] = dinv;
  }
}

// TRSM: L21 = A21 * inv(L11)^H  (L11 staged column-major in LDS)
__global__ __launch_bounds__(256) void k_trsm(double2* A, const double* invd, int j0){
  __shared__ double2 Lp[65*65];   // Lp[c*65 + i] = L11[i][c]
  __shared__ double ivp[65];
  int tid = threadIdx.x;
  for (int e = tid; e < 65*65; e += 256){
    int i = e / 65, c = e - i*65;
    Lp[c*65 + i] = A[(size_t)(j0+i)*NE + j0 + c];
  }
  if (tid < 65) ivp[tid] = invd[j0 + tid];
  __syncthreads();
  int lane = tid & 63, wid = tid >> 6;
  int rg = j0 + 65 + blockIdx.x*4 + wid;
  if (rg >= NE) return;
  double2 a0 = A[(size_t)rg*NE + j0 + lane];
  double2 a64 = (lane == 0) ? A[(size_t)rg*NE + j0 + 64] : make_double2(0,0);
  for (int c = 0; c < 65; ++c){
    double xr, xi;
    if (c < 64){ xr = __shfl(a0.x, c, 64); xi = __shfl(a0.y, c, 64); }
    else { xr = __shfl(a64.x, 0, 64); xi = __shfl(a64.y, 0, 64); }
    double iv = ivp[c];
    xr *= iv; xi *= iv;
    if (c < 64){ if (lane == c){ a0.x = xr; a0.y = xi; } }
    else if (lane == 0){ a64.x = xr; a64.y = xi; }
    if (lane > c){
      double2 l = Lp[c*65 + lane];
      a0.x -= xr*l.x + xi*l.y; a0.y -= xi*l.x - xr*l.y;
    }
    if (lane == 0 && c < 64){
      double2 l = Lp[c*65 + 64];
      a64.x -= xr*l.x + xi*l.y; a64.y -= xi*l.x - xr*l.y;
    }
  }
  A[(size_t)rg*NE + j0 + lane] = a0;
  if (lane == 0) A[(size_t)rg*NE + j0 + 64] = a64;
}

// SYRK: A22 -= L21 L21^H (lower only)
__global__ __launch_bounds__(256) void k_syrk(double2* A, int j0){
  if (blockIdx.y > blockIdx.x) return;
  int j1 = j0 + 65;
  int i0 = j1 + blockIdx.x*32, t0 = j1 + blockIdx.y*32;
  __shared__ double2 Li[32][17];
  __shared__ double2 Lt[32][17];
  int tid = threadIdx.x;
  int oi = tid >> 3, tj = (tid & 7)*4;
  double2 acc[4] = {make_double2(0,0),make_double2(0,0),make_double2(0,0),make_double2(0,0)};
  for (int c0 = 0; c0 < 65; c0 += 16){
    int cw = min(16, 65 - c0);
    __syncthreads();
    for (int e = tid; e < 512; e += 256){
      int r = e >> 4, c = e & 15;
      double2 zi = make_double2(0,0), zt = zi;
      if (c < cw){
        if (i0 + r < NE) zi = A[(size_t)(i0+r)*NE + j0 + c0 + c];
        if (t0 + r < NE) zt = A[(size_t)(t0+r)*NE + j0 + c0 + c];
      }
      Li[r][c] = zi; Lt[r][c] = zt;
    }
    __syncthreads();
    for (int c = 0; c < cw; ++c){
      double2 li = Li[oi][c];
      #pragma unroll
      for (int j = 0; j < 4; ++j){
        double2 lt = Lt[tj+j][c];
        acc[j].x += li.x*lt.x + li.y*lt.y;
        acc[j].y += li.y*lt.x - li.x*lt.y;
      }
    }
  }
  int gi = i0 + oi;
  if (gi < NE){
    #pragma unroll
    for (int j = 0; j < 4; ++j){
      int gt = t0 + tj + j;
      if (gt < NE && gt <= gi){
        double2 v = A[(size_t)gi*NE + gt];
        v.x -= acc[j].x; v.y -= acc[j].y;
        A[(size_t)gi*NE + gt] = v;
      }
    }
  }
}

// LT[c*576+t] = A[t*NE+c] for t>c (t<520), else 0.  (column-major L, zero-padded)
__global__ __launch_bounds__(256) void k_tr(const double2* A, double2* LT){
  __shared__ double2 tl[32][33];
  int bc = blockIdx.x*32;   // column (c) tile base
  int bt = blockIdx.y*32;   // row (t) tile base
  int lx = threadIdx.x & 31, ly = threadIdx.x >> 5;   // 8 rows per pass
  #pragma unroll
  for (int rr = 0; rr < 32; rr += 8){
    int t = bt + ly + rr, c = bc + lx;
    double2 v = make_double2(0,0);
    if (t < NE && c < NE && t > c) v = A[(size_t)t*NE + c];
    tl[ly+rr][lx] = v;
  }
  __syncthreads();
  #pragma unroll
  for (int rr = 0; rr < 32; rr += 8){
    int c = bc + ly + rr, t = bt + lx;
    if (c < NE) LT[(size_t)c*576 + t] = tl[lx][ly+rr];
  }
}

// RZ[c*576+t] = A[c*NE+t] for t<c, else 0.   (rows of L, zero-padded)
__global__ __launch_bounds__(256) void k_rz(const double2* A, double2* RZ){
  int idx = blockIdx.x*256 + threadIdx.x;   // over 520*576
  if (idx >= NE*576) return;
  int c = idx / 576, t = idx - c*576;
  double2 v = (t < c) ? A[(size_t)c*NE + t] : make_double2(0,0);
  RZ[idx] = v;
}

// ---- solve helpers: independent waves, register ping-pong pipeline ----

// load column cc of LT (rows blocks r >= cc>>6) into buf
__device__ __forceinline__ void ldcol_f(const double2* __restrict__ LT, int cc, int n,
                                        int lane, double2 (&buf)[9]){
  if (cc < n){
    int rlo = cc >> 6;
    const double2* p = LT + (size_t)cc*576 + lane;
    #pragma unroll
    for (int r = 0; r < 9; ++r) if (r >= rlo) buf[r] = p[r*64];
  }
}

// load column cc of RZ (row blocks r <= cc>>6) into buf
__device__ __forceinline__ void ldcol_b(const double2* __restrict__ RZ, int cc,
                                        int lane, double2 (&buf)[9]){
  if (cc >= 0){
    int rhi = cc >> 6;
    const double2* p = RZ + (size_t)cc*576 + lane;
    #pragma unroll
    for (int r = 0; r < 9; ++r) if (r <= rhi) buf[r] = p[r*64];
  }
}

template<int RR>
__device__ __forceinline__ void pf1(double2 (&y)[9], const double2 (&buf)[9],
                                    double iv, int la, int lane){
  double xr = __shfl(y[RR].x, la, 64)*iv;
  double xi = __shfl(y[RR].y, la, 64)*iv;
  if (lane == la){ y[RR].x = xr; y[RR].y = xi; }
  #pragma unroll
  for (int r = RR; r < 9; ++r){
    double2 l = buf[r];                 // LT zero for t<=c and t>=520
    y[r].x -= l.x*xr - l.y*xi;
    y[r].y -= l.x*xi + l.y*xr;
  }
}

template<int RR>
__device__ __forceinline__ void pb1(double2 (&y)[9], const double2 (&buf)[9],
                                    double iv, int la, int lane){
  double xr = __shfl(y[RR].x, la, 64)*iv;
  double xi = __shfl(y[RR].y, la, 64)*iv;
  if (lane == la){ y[RR].x = xr; y[RR].y = xi; }
  #pragma unroll
  for (int r = 0; r <= RR; ++r){
    double2 l = buf[r];                 // RZ zero for t>=c
    y[r].x -= l.x*xr + l.y*xi;
    y[r].y -= l.x*xi - l.y*xr;
  }
}

// forward panel RR: columns [RR*64, RR*64+ncol), A holds first column on entry;
// on exit A holds column RR*64+ncol (if < n)
template<int RR>
__device__ __forceinline__ void panel_f(const double2* __restrict__ LT,
    const double* __restrict__ invd, double2 (&y)[9],
    double2 (&A)[9], double2 (&Bb)[9], int n, int lane){
  int cb = RR*64;
  int ncol = min(64, n - cb);           // 64, or 8 for RR=8/n=520 (always even)
  for (int k = 0; k < ncol; k += 2){
    int c = cb + k;
    double iv0 = invd[c];
    double iv1 = (k+1 < ncol) ? invd[c+1] : 0.0;
    ldcol_f(LT, c+1, n, lane, Bb);
    pf1<RR>(y, A, iv0, c & 63, lane);
    ldcol_f(LT, c+2, n, lane, A);
    if (k+1 < ncol) pf1<RR>(y, Bb, iv1, (c+1) & 63, lane);
  }
}

// backward panel RR: columns from RR*64+ncol-1 down to RR*64; A holds top column
// on entry; on exit A holds column RR*64-1 (if >= 0)
template<int RR>
__device__ __forceinline__ void panel_b(const double2* __restrict__ RZ,
    const double* __restrict__ invd, double2 (&y)[9],
    double2 (&A)[9], double2 (&Bb)[9], int n, int lane){
  int cb = RR*64;
  int ncol = min(64, n - cb);
  int ce = cb + ncol - 1;
  for (int k = 0; k < ncol; k += 2){
    int c = ce - k;
    double iv0 = invd[c];
    double iv1 = (k+1 < ncol) ? invd[c-1] : 0.0;
    ldcol_b(RZ, c-1, lane, Bb);
    pb1<RR>(y, A, iv0, c & 63, lane);
    ldcol_b(RZ, c-2, lane, A);
    if (k+1 < ncol) pb1<RR>(y, Bb, iv1, (c-1) & 63, lane);
  }
}

// forward+backward substitution; 256 blocks x 4 waves, 1 RHS per wave,
// fully independent waves (no LDS, no barriers), ping-pong register prefetch,
// structurally-zero row blocks skipped.
__global__ __launch_bounds__(256) void k_solve(const double2* __restrict__ LT,
    const double2* __restrict__ RZ, const double* __restrict__ invd,
    double2* B0, double2* B1){
  int tid = threadIdx.x, lane = tid & 63, z = tid >> 6;
  int w = blockIdx.x*4 + z;                 // 0..1023
  int sys = (w >= 512) ? 1 : 0;
  int c0 = sys ? (w - 512) : w;
  int n = sys ? NO : NE;
  double2* B = sys ? B1 : B0;
  double2 y[9];
  #pragma unroll
  for (int r = 0; r < 9; ++r){
    int t = r*64 + lane;
    y[r] = (t < n) ? B[(size_t)t*512 + c0] : make_double2(0,0);
  }
  double2 A[9], Bb[9];

  // ---------- forward ----------
  ldcol_f(LT, 0, n, lane, A);
  panel_f<0>(LT, invd, y, A, Bb, n, lane);
  panel_f<1>(LT, invd, y, A, Bb, n, lane);
  panel_f<2>(LT, invd, y, A, Bb, n, lane);
  panel_f<3>(LT, invd, y, A, Bb, n, lane);
  panel_f<4>(LT, invd, y, A, Bb, n, lane);
  panel_f<5>(LT, invd, y, A, Bb, n, lane);
  panel_f<6>(LT, invd, y, A, Bb, n, lane);
  panel_f<7>(LT, invd, y, A, Bb, n, lane);
  if (n > 512) panel_f<8>(LT, invd, y, A, Bb, n, lane);

  // ---------- backward ----------
  ldcol_b(RZ, n-1, lane, A);
  if (n > 512) panel_b<8>(RZ, invd, y, A, Bb, n, lane);
  panel_b<7>(RZ, invd, y, A, Bb, n, lane);
  panel_b<6>(RZ, invd, y, A, Bb, n, lane);
  panel_b<5>(RZ, invd, y, A, Bb, n, lane);
  panel_b<4>(RZ, invd, y, A, Bb, n, lane);
  panel_b<3>(RZ, invd, y, A, Bb, n, lane);
  panel_b<2>(RZ, invd, y, A, Bb, n, lane);
  panel_b<1>(RZ, invd, y, A, Bb, n, lane);
  panel_b<0>(RZ, invd, y, A, Bb, n, lane);

  #pragma unroll
  for (int r = 0; r < 9; ++r){
    int t = r*64 + lane;
    if (t < n) B[(size_t)t*512 + c0] = y[r];
  }
}

// eta output (interleave even/odd systems, f64 -> f32)
__global__ __launch_bounds__(256) void k_eta(const double2* B0, const double2* B1,
                                             float* out_eta, int cpx){
  int idx = blockIdx.x*256 + threadIdx.x;
  if (idx >= NQ*512) return;
  int q = idx >> 9;
  int m = idx & 511;
  int n = q >> 3, k = q & 7;
  const double2* B = (n & 1) ? B1 : B0;
  int hr = (n >> 1)*8 + k;
  double2 v = B[(size_t)hr*512 + m];
  if (cpx) ((float2*)out_eta)[idx] = make_float2((float)v.x, (float)v.y);
  else     out_eta[idx] = (float)v.x;
}

// fused: b output + g_est output + bsel extraction (BSEL scratch stays complex)
__global__ __launch_bounds__(256) void k_gestb(const double2* B0, const double2* B1,
    const float* psi32, const float* thc32, const float* ths32,
    float* out_b, float* out_g, float2* BSEL, int cpx){
  int m = blockIdx.x; int p = blockIdx.y*256 + threadIdx.x;
  __shared__ float4 eL4[516];
  float2* eL2 = (float2*)eL4;
  for (int e = threadIdx.x; e < NQ; e += 256){
    int n = e >> 3, k = e & 7;
    const double2* B = (n & 1) ? B1 : B0;
    double2 v = B[(size_t)((n >> 1)*8 + k)*512 + m];
    eL2[e] = make_float2((float)v.x, (float)v.y);
  }
  __syncthreads();
  float pr[8];
  #pragma unroll
  for (int k = 0; k < 8; ++k) pr[k] = psi32[k*1024+p];
  float aEx=0, aEy=0, aOx=0, aOy=0;
  size_t bbase = (size_t)m*129*1024 + p;
  for (int n = 0; n < 129; ++n){
    float c = thc32[n*1024+p], s = ths32[n*1024+p];
    float4 e0 = eL4[n*4+0], e1 = eL4[n*4+1], e2 = eL4[n*4+2], e3 = eL4[n*4+3];
    float br = e0.x*pr[0] + e0.z*pr[1] + e1.x*pr[2] + e1.z*pr[3]
             + e2.x*pr[4] + e2.z*pr[5] + e3.x*pr[6] + e3.z*pr[7];
    float bi = e0.y*pr[0] + e0.w*pr[1] + e1.y*pr[2] + e1.w*pr[3]
             + e2.y*pr[4] + e2.w*pr[5] + e3.y*pr[6] + e3.w*pr[7];
    if (cpx) ((float2*)out_b)[bbase + (size_t)n*1024] = make_float2(br, bi);
    else     out_b[bbase + (size_t)n*1024] = br;
    if ((p & 127) == 0) BSEL[(size_t)m*NQ + n*8 + (p >> 7)] = make_float2(br, bi);
    float tr = c*br - s*bi, ti = c*bi + s*br;
    if (n & 1){ aOx += tr; aOy += ti; } else { aEx += tr; aEy += ti; }
  }
  if (cpx){
    ((float2*)out_g)[(size_t)m*2048 + p]        = make_float2(aEx+aOx, aEy+aOy);
    ((float2*)out_g)[(size_t)m*2048 + p + 1024] = make_float2(aEx-aOx, aEy-aOy);
  } else {
    out_g[(size_t)m*2048 + p]        = aEx+aOx;
    out_g[(size_t)m*2048 + p + 1024] = aEx-aOx;
  }
}

// f_pol_est_s output
__global__ __launch_bounds__(256) void k_fpol(const float2* BSEL, const float* thc32,
    const float* ths32, float* out_f, int cpx){
  int m = blockIdx.x; int p = blockIdx.y*256 + threadIdx.x;
  __shared__ float4 bs4[516];
  float2* bs2 = (float2*)bs4;
  for (int e = threadIdx.x; e < NQ; e += 256) bs2[e] = BSEL[(size_t)m*NQ + e];
  __syncthreads();
  float ar[8] = {0,0,0,0,0,0,0,0}, ai[8] = {0,0,0,0,0,0,0,0};
  for (int n = 0; n < 129; ++n){
    float c = thc32[n*1024+p], s = ths32[n*1024+p];
    #pragma unroll
    for (int jj = 0; jj < 4; ++jj){
      float4 v = bs4[n*4+jj];
      ar[2*jj]   += c*v.x - s*v.y;  ai[2*jj]   += c*v.y + s*v.x;
      ar[2*jj+1] += c*v.z - s*v.w;  ai[2*jj+1] += c*v.w + s*v.z;
    }
  }
  if (cpx){
    float4* o = (float4*)(out_f + ((size_t)m*1024 + p)*16);
    o[0] = make_float4(ar[0],ai[0],ar[1],ai[1]);
    o[1] = make_float4(ar[2],ai[2],ar[3],ai[3]);
    o[2] = make_float4(ar[4],ai[4],ar[5],ai[5]);
    o[3] = make_float4(ar[6],ai[6],ar[7],ai[7]);
  } else {
    float4* o = (float4*)(out_f + ((size_t)m*1024 + p)*8);
    o[0] = make_float4(ar[0],ar[1],ar[2],ar[3]);
    o[1] = make_float4(ar[4],ar[5],ar[6],ar[7]);
  }
}

extern "C" void kernel_launch(void* const* d_in, const int* in_sizes, int n_in,
                              void* d_out, int out_size, void* d_ws, size_t ws_size,
                              hipStream_t stream){
  const float* g     = (const float*)d_in[0];
  const float* tf    = (const float*)d_in[1];
  const float* theta = (const float*)d_in[2];
  float* out = (float*)d_out;

  int cpx = (out_size >= C_TOTAL) ? 1 : 0;
  float* o_eta = out + (cpx ? C_ETA : R_ETA);
  float* o_l1  = out + (cpx ? C_L1  : R_L1);
  float* o_g   = out + (cpx ? C_G   : R_G);
  float* o_b   = out + (cpx ? C_B   : R_B);
  float* o_f   = out + (cpx ? C_F   : R_F);
  float* o_psi = out + (cpx ? C_PSI : R_PSI);

  // scratch pools: prefer d_ws when large enough, else carve from late-written outputs
  size_t need = (size_t)SB_TOTAL + (size_t)SL_TOTALF*4 + 4096;
  char*  sb;     // fp64 pool base
  float* sl;     // fp32 pool base
  if (ws_size >= need){
    sb = (char*)d_ws;
    sl = (float*)((char*)d_ws + SB_TOTAL);
  } else {
    sb = (char*)o_b;   // o_b region: >=270 MB (real) / 541 MB (cpx), dead until k_gestb
    sl = o_l1;         // o_l1 region: >=2.1M floats, dead until k_l1out (runs last)
  }
  float*   psi32 = sl + SL_PSI32;
  float*   thc32 = sl + SL_THC32;
  float*   ths32 = sl + SL_THS32;
  float2*  BSEL  = (float2*)(sl + SL_BSEL);
  double*  psi64 = (double*)(sb + SB_PSI64);
  double*  thc64 = (double*)(sb + SB_THC64);
  double*  ths64 = (double*)(sb + SB_THS64);
  double2* Ct    = (double2*)(sb + SB_CT);
  double2* A0    = (double2*)(sb + SB_A0);
  double2* B0    = (double2*)(sb + SB_B0);
  double2* B1    = (double2*)(sb + SB_B1);
  double*  INVD  = (double*)(sb + SB_INVD);
  double2* LT    = (double2*)(sb + SB_LT);
  double2* RZ    = (double2*)(sb + SB_RZ);

  k_prep <<<548, 256, 0, stream>>>(tf, theta, psi32, psi64, thc64, ths64, thc32, ths32, o_psi, cpx);
  k_ctab <<<65, 256, 0, stream>>>(theta, psi64, Ct);
  k_afill<<<1057, 256, 0, stream>>>(Ct, A0);
  k_bgemm<<<dim3(129,4), 256, 0, stream>>>(g, thc64, ths64, psi64, B0, B1);
  for (int s = 0; s < 8; ++s){
    k_potrf<<<1, 256, 0, stream>>>(A0, INVD, s*65);
    int rem = NE - 65*(s+1);
    if (rem > 0){
      k_trsm<<<(rem+3)/4, 256, 0, stream>>>(A0, INVD, s*65);
      int nt = (rem+31)/32;
      k_syrk<<<dim3(nt,nt), 256, 0, stream>>>(A0, s*65);
    }
  }
  k_tr   <<<dim3(17,18), 256, 0, stream>>>(A0, LT);
  k_rz   <<<(NE*576 + 255)/256, 256, 0, stream>>>(A0, RZ);
  k_solve<<<256, 256, 0, stream>>>(LT, RZ, INVD, B0, B1);
  k_eta  <<<2064, 256, 0, stream>>>(B0, B1, o_eta, cpx);
  k_gestb<<<dim3(512,4), 256, 0, stream>>>(B0, B1, psi32, thc32, ths32, o_b, o_g, BSEL, cpx);
  k_fpol <<<dim3(512,4), 256, 0, stream>>>(BSEL, thc32, ths32, o_f, cpx);
  k_l1out<<<2048, 256, 0, stream>>>(tf, theta, o_l1, cpx);
}

// Round 4
// 1662.657 us; speedup vs baseline: 1.3534x; 1.0085x over previous
//
#include <hip/hip_runtime.h>

#define NQ 1032
#define NE 520
#define NO 512

// ---- output offsets, complex-interleaved mode (floats) ----
#define C_ETA 0
#define C_L1  1056768
#define C_G   5283840
#define C_B   7380992
#define C_F   142647296
#define C_PSI 151035904
#define C_TOTAL 151052288

// ---- output offsets, real-only mode (floats) ----
#define R_ETA 0
#define R_L1  528384
#define R_G   2641920
#define R_B   3690496
#define R_F   71323648
#define R_PSI 75517952

// ---- fp32 scratch pool (float offsets; in d_ws or carved from o_l1 region) ----
#define SL_PSI32 0
#define SL_THC32 9216
#define SL_THS32 142336
#define SL_BSEL  275456
#define SL_TOTALF 1332224   // floats (o_l1 region >= 2,113,536 floats even in real mode)

// ---- fp64 scratch pool (byte offsets; in d_ws or carved from o_b region) ----
#define SB_PSI64 0
#define SB_THC64 69632
#define SB_THS64 1130496
#define SB_CT    2191360
#define SB_A0    2262016
#define SB_B0    6592512
#define SB_B1    10856448
#define SB_INVD  15054848
#define SB_LT    15059008
#define SB_RZ    19851328
#define SB_TOTAL 24643648   // bytes (o_b region >= 270 MB even in real mode)

__device__ inline void tri_it(int e, int& i, int& t){
  int ii = (int)((sqrt(8.0*(double)e + 1.0) - 1.0) * 0.5);
  int base = (ii*(ii+1)) >> 1;
  while (base + ii + 1 <= e){ base += ii + 1; ++ii; }
  while (base > e){ base -= ii; --ii; }
  i = ii; t = e - base;
}

// psi interp + theta cos/sin tables + psi_mtx output
__global__ __launch_bounds__(256) void k_prep(const float* tf, const float* theta,
    float* psi32, double* psi64, double* thc64, double* ths64,
    float* thc32, float* ths32, float* o_psi, int cpx){
  int idx = blockIdx.x*256 + threadIdx.x;
  if (idx < 8192){
    int k = idx >> 10, p = idx & 1023;
    double x = 0.25*(double)p - 0.375;
    x = fmin(fmax(x, 0.0), 255.0);
    int x0 = (int)x;
    int x1 = min(x0+1, 255);
    double w = x - (double)x0;
    double v = (double)tf[k*256+x0]*(1.0-w) + (double)tf[k*256+x1]*w;
    psi64[k*1024+p] = v;
    float vf = (float)v;
    psi32[k*1024+p] = vf;
    if (cpx){ o_psi[idx*2+0] = vf; o_psi[idx*2+1] = 0.f; }
    else    { o_psi[idx] = vf; }
  } else {
    int j = idx - 8192;
    if (j < 129*1024){
      int n = j >> 10, p = j & 1023;
      double a = (double)(n-64)*(double)theta[p];
      double c = cos(a), s = sin(a);
      thc64[j] = c; ths64[j] = s;
      thc32[j] = (float)c; ths32[j] = (float)s;
    }
  }
}

// L1 output: self-contained; runs LAST (clobbers fp32 scratch if carved).
__global__ __launch_bounds__(256) void k_l1out(const float* tf, const float* theta,
    float* out_l1, int cpx){
  int row = blockIdx.x; int p = row & 1023; int bot = row >> 10;
  __shared__ float cc[129], ss[129], pp[8];
  int tid = threadIdx.x;
  float th = theta[p];
  if (tid < 129){
    float a = (float)(tid - 64) * th;
    cc[tid] = cosf(a); ss[tid] = sinf(a);
  }
  if (tid >= 192 && tid < 200){
    int k = tid - 192;
    float x = 0.25f*(float)p - 0.375f;
    x = fminf(fmaxf(x, 0.f), 255.f);
    int x0 = (int)x;
    int x1 = min(x0+1, 255);
    float w = x - (float)x0;
    pp[k] = tf[k*256+x0]*(1.f-w) + tf[k*256+x1]*w;
  }
  __syncthreads();
  for (int q = tid; q < NQ; q += 256){
    int n = q >> 3, k = q & 7;
    float sg = (bot && (n & 1)) ? -1.f : 1.f;
    float w = pp[k]*sg;
    if (cpx) ((float2*)out_l1)[(size_t)row*NQ + q] = make_float2(cc[n]*w, ss[n]*w);
    else     out_l1[(size_t)row*NQ + q] = cc[n]*w;
  }
}

// C[d][k][k'] = sum_p exp(i*2d*theta_p) psi_k psi_k'
// psi + cos/sin staged in LDS; 36 pairs round-robin over 4 waves, no per-pair barriers.
__global__ __launch_bounds__(256) void k_ctab(const float* theta, const double* psi64, double2* C){
  int t = blockIdx.x; double dd = 2.0*(double)t;
  __shared__ double cs[1024], sn[1024];
  __shared__ double ps[8][1024];
  int tid = threadIdx.x;
  for (int p = tid; p < 1024; p += 256){ double a = dd*(double)theta[p]; cs[p] = cos(a); sn[p] = sin(a); }
  for (int e = tid; e < 8192; e += 256) ps[e >> 10][e & 1023] = psi64[e];
  __syncthreads();
  int lane = tid & 63, wid = tid >> 6;
  int cnt = 0;
  for (int k = 0; k < 8; ++k){
    for (int k2 = k; k2 < 8; ++k2){
      if ((cnt & 3) == wid){
        double sr = 0, si = 0;
        for (int p = lane; p < 1024; p += 64){
          double w = ps[k][p]*ps[k2][p];
          sr += cs[p]*w; si += sn[p]*w;
        }
        #pragma unroll
        for (int o = 32; o > 0; o >>= 1){ sr += __shfl_down(sr, o, 64); si += __shfl_down(si, o, 64); }
        if (lane == 0){
          C[t*64 + k*8 + k2] = make_double2(sr, si);
          C[t*64 + k2*8 + k] = make_double2(sr, si);
        }
      }
      ++cnt;
    }
  }
}

// A0[(i,k),(j,k')] = 2*C[j-i][k][k'] (conj for j<i)
__global__ __launch_bounds__(256) void k_afill(const double2* C, double2* A){
  int idx = blockIdx.x*256 + threadIdx.x;
  if (idx >= NE*NE) return;
  int r = idx / NE, cix = idx - r*NE;
  int k = r & 7, i = r >> 3, j = cix >> 3, k2 = cix & 7;
  int dt = j - i;
  double2 v;
  if (dt >= 0){ v = C[dt*64 + k*8 + k2]; v.x *= 2.0; v.y *= 2.0; }
  else { v = C[(-dt)*64 + k*8 + k2]; v.x *= 2.0; v.y *= -2.0; }
  A[idx] = v;
}

// B = L1^H g via structure
__global__ __launch_bounds__(256) void k_bgemm(const float* g, const double* thc64, const double* ths64,
    const double* psi64, double2* B0, double2* B1){
  int n = blockIdx.x; int m0 = blockIdx.y * 128;
  int par = n & 1;
  __shared__ float u[64][129];
  __shared__ double cs[64], sn[64], ps[8][64];
  int tid = threadIdx.x;
  int k = tid >> 5, mg = tid & 31;
  double ar[4] = {0,0,0,0}, ai[4] = {0,0,0,0};
  for (int p0 = 0; p0 < 1024; p0 += 64){
    __syncthreads();
    if (tid < 64){ cs[tid] = thc64[n*1024 + p0 + tid]; sn[tid] = ths64[n*1024 + p0 + tid]; }
    for (int e = tid; e < 512; e += 256){ int kk = e >> 6, pp = e & 63; ps[kk][pp] = psi64[kk*1024 + p0 + pp]; }
    for (int e = tid; e < 2048; e += 256){
      int m = e >> 4, p4 = (e & 15) * 4;
      const float4 a = *(const float4*)(g + (size_t)(m0+m)*2048 + p0 + p4);
      const float4 b = *(const float4*)(g + (size_t)(m0+m)*2048 + 1024 + p0 + p4);
      float4 uu;
      if (par){ uu.x = a.x-b.x; uu.y = a.y-b.y; uu.z = a.z-b.z; uu.w = a.w-b.w; }
      else    { uu.x = a.x+b.x; uu.y = a.y+b.y; uu.z = a.z+b.z; uu.w = a.w+b.w; }
      u[p4+0][m] = uu.x; u[p4+1][m] = uu.y; u[p4+2][m] = uu.z; u[p4+3][m] = uu.w;
    }
    __syncthreads();
    for (int p = 0; p < 64; ++p){
      double w = ps[k][p];
      double wr = cs[p]*w, wi = sn[p]*w;
      #pragma unroll
      for (int j = 0; j < 4; ++j){
        double uu = (double)u[p][mg + 32*j];
        ar[j] += wr*uu; ai[j] -= wi*uu;
      }
    }
  }
  int hr = (n >> 1)*8 + k;
  double2* B = par ? B1 : B0;
  #pragma unroll
  for (int j = 0; j < 4; ++j) B[(size_t)hr*512 + m0 + mg + 32*j] = make_double2(ar[j], ai[j]);
}

// panel Cholesky 65x65 (packed lower triangle in LDS)
__global__ __launch_bounds__(256) void k_potrf(double2* A, double* invd, int j0){
  __shared__ double2 T[2145];
  int tid = threadIdx.x;
  for (int e = tid; e < 2145; e += 256){
    int i, t; tri_it(e, i, t);
    T[e] = A[(size_t)(j0+i)*NE + j0 + t];
  }
  __syncthreads();
  for (int j = 0; j < 65; ++j){
    double inv = 1.0 / T[(j*(j+1))/2 + j].x;
    int i = j + 1 + (tid & 63);
    if (i < 65){
      double2 lij = T[(i*(i+1))/2 + j];
      for (int t = j+1+(tid>>6); t <= i; t += 4){
        double2 ltj = T[(t*(t+1))/2 + j];
        double2 a = T[(i*(i+1))/2 + t];
        a.x -= (lij.x*ltj.x + lij.y*ltj.y)*inv;
        a.y -= (lij.y*ltj.x - lij.x*ltj.y)*inv;
        T[(i*(i+1))/2 + t] = a;
      }
    }
    __syncthreads();
  }
  for (int e = tid; e < 2145; e += 256){
    int i, t; tri_it(e, i, t);
    double dinv = 1.0 / sqrt(T[(t*(t+1))/2 + t].x);
    double2 v = T[e]; v.x *= dinv; v.y *= dinv;
    A[(size_t)(j0+i)*NE + j0 + t] = v;
    if (i == t) invd[j0+i] = dinv;
  }
}

// TRSM: L21 = A21 * inv(L11)^H  (L11 staged column-major in LDS)
__global__ __launch_bounds__(256) void k_trsm(double2* A, const double* invd, int j0){
  __shared__ double2 Lp[65*65];   // Lp[c*65 + i] = L11[i][c]
  __shared__ double ivp[65];
  int tid = threadIdx.x;
  for (int e = tid; e < 65*65; e += 256){
    int i = e / 65, c = e - i*65;
    Lp[c*65 + i] = A[(size_t)(j0+i)*NE + j0 + c];
  }
  if (tid < 65) ivp[tid] = invd[j0 + tid];
  __syncthreads();
  int lane = tid & 63, wid = tid >> 6;
  int rg = j0 + 65 + blockIdx.x*4 + wid;
  if (rg >= NE) return;
  double2 a0 = A[(size_t)rg*NE + j0 + lane];
  double2 a64 = (lane == 0) ? A[(size_t)rg*NE + j0 + 64] : make_double2(0,0);
  for (int c = 0; c < 65; ++c){
    double xr, xi;
    if (c < 64){ xr = __shfl(a0.x, c, 64); xi = __shfl(a0.y, c, 64); }
    else { xr = __shfl(a64.x, 0, 64); xi = __shfl(a64.y, 0, 64); }
    double iv = ivp[c];
    xr *= iv; xi *= iv;
    if (c < 64){ if (lane == c){ a0.x = xr; a0.y = xi; } }
    else if (lane == 0){ a64.x = xr; a64.y = xi; }
    if (lane > c){
      double2 l = Lp[c*65 + lane];
      a0.x -= xr*l.x + xi*l.y; a0.y -= xi*l.x - xr*l.y;
    }
    if (lane == 0 && c < 64){
      double2 l = Lp[c*65 + 64];
      a64.x -= xr*l.x + xi*l.y; a64.y -= xi*l.x - xr*l.y;
    }
  }
  A[(size_t)rg*NE + j0 + lane] = a0;
  if (lane == 0) A[(size_t)rg*NE + j0 + 64] = a64;
}

// SYRK: A22 -= L21 L21^H (lower only)
__global__ __launch_bounds__(256) void k_syrk(double2* A, int j0){
  if (blockIdx.y > blockIdx.x) return;
  int j1 = j0 + 65;
  int i0 = j1 + blockIdx.x*32, t0 = j1 + blockIdx.y*32;
  __shared__ double2 Li[32][17];
  __shared__ double2 Lt[32][17];
  int tid = threadIdx.x;
  int oi = tid >> 3, tj = (tid & 7)*4;
  double2 acc[4] = {make_double2(0,0),make_double2(0,0),make_double2(0,0),make_double2(0,0)};
  for (int c0 = 0; c0 < 65; c0 += 16){
    int cw = min(16, 65 - c0);
    __syncthreads();
    for (int e = tid; e < 512; e += 256){
      int r = e >> 4, c = e & 15;
      double2 zi = make_double2(0,0), zt = zi;
      if (c < cw){
        if (i0 + r < NE) zi = A[(size_t)(i0+r)*NE + j0 + c0 + c];
        if (t0 + r < NE) zt = A[(size_t)(t0+r)*NE + j0 + c0 + c];
      }
      Li[r][c] = zi; Lt[r][c] = zt;
    }
    __syncthreads();
    for (int c = 0; c < cw; ++c){
      double2 li = Li[oi][c];
      #pragma unroll
      for (int j = 0; j < 4; ++j){
        double2 lt = Lt[tj+j][c];
        acc[j].x += li.x*lt.x + li.y*lt.y;
        acc[j].y += li.y*lt.x - li.x*lt.y;
      }
    }
  }
  int gi = i0 + oi;
  if (gi < NE){
    #pragma unroll
    for (int j = 0; j < 4; ++j){
      int gt = t0 + tj + j;
      if (gt < NE && gt <= gi){
        double2 v = A[(size_t)gi*NE + gt];
        v.x -= acc[j].x; v.y -= acc[j].y;
        A[(size_t)gi*NE + gt] = v;
      }
    }
  }
}

// LT[c*576+t] = A[t*NE+c] for t>c (t<520), else 0.  (column-major L, zero-padded)
__global__ __launch_bounds__(256) void k_tr(const double2* A, double2* LT){
  __shared__ double2 tl[32][33];
  int bc = blockIdx.x*32;   // column (c) tile base
  int bt = blockIdx.y*32;   // row (t) tile base
  int lx = threadIdx.x & 31, ly = threadIdx.x >> 5;   // 8 rows per pass
  #pragma unroll
  for (int rr = 0; rr < 32; rr += 8){
    int t = bt + ly + rr, c = bc + lx;
    double2 v = make_double2(0,0);
    if (t < NE && c < NE && t > c) v = A[(size_t)t*NE + c];
    tl[ly+rr][lx] = v;
  }
  __syncthreads();
  #pragma unroll
  for (int rr = 0; rr < 32; rr += 8){
    int c = bc + ly + rr, t = bt + lx;
    if (c < NE) LT[(size_t)c*576 + t] = tl[lx][ly+rr];
  }
}

// RZ[c*576+t] = A[c*NE+t] for t<c, else 0.   (rows of L, zero-padded)
__global__ __launch_bounds__(256) void k_rz(const double2* A, double2* RZ){
  int idx = blockIdx.x*256 + threadIdx.x;   // over 520*576
  if (idx >= NE*576) return;
  int c = idx / 576, t = idx - c*576;
  double2 v = (t < c) ? A[(size_t)c*NE + t] : make_double2(0,0);
  RZ[idx] = v;
}

// ---- solve helpers: independent waves, 4-deep register pipeline ----

// load column cc of LT (rows blocks r >= cc>>6) into buf
__device__ __forceinline__ void ldcol_f(const double2* __restrict__ LT, int cc, int n,
                                        int lane, double2 (&buf)[9]){
  if (cc < n){
    int rlo = cc >> 6;
    const double2* p = LT + (size_t)cc*576 + lane;
    #pragma unroll
    for (int r = 0; r < 9; ++r) if (r >= rlo) buf[r] = p[r*64];
  }
}

// load column cc of RZ (row blocks r <= cc>>6) into buf
__device__ __forceinline__ void ldcol_b(const double2* __restrict__ RZ, int cc,
                                        int lane, double2 (&buf)[9]){
  if (cc >= 0){
    int rhi = cc >> 6;
    const double2* p = RZ + (size_t)cc*576 + lane;
    #pragma unroll
    for (int r = 0; r < 9; ++r) if (r <= rhi) buf[r] = p[r*64];
  }
}

template<int RR>
__device__ __forceinline__ void pf1(double2 (&y)[9], const double2 (&buf)[9],
                                    double iv, int la, int lane){
  double xr = __shfl(y[RR].x, la, 64)*iv;
  double xi = __shfl(y[RR].y, la, 64)*iv;
  if (lane == la){ y[RR].x = xr; y[RR].y = xi; }
  #pragma unroll
  for (int r = RR; r < 9; ++r){
    double2 l = buf[r];                 // LT zero for t<=c and t>=520
    y[r].x -= l.x*xr - l.y*xi;
    y[r].y -= l.x*xi + l.y*xr;
  }
}

template<int RR>
__device__ __forceinline__ void pb1(double2 (&y)[9], const double2 (&buf)[9],
                                    double iv, int la, int lane){
  double xr = __shfl(y[RR].x, la, 64)*iv;
  double xi = __shfl(y[RR].y, la, 64)*iv;
  if (lane == la){ y[RR].x = xr; y[RR].y = xi; }
  #pragma unroll
  for (int r = 0; r <= RR; ++r){
    double2 l = buf[r];                 // RZ zero for t>=c
    y[r].x -= l.x*xr + l.y*xi;
    y[r].y -= l.x*xi - l.y*xr;
  }
}

// forward panel RR: columns [RR*64, RR*64+ncol); on entry A,B,C,D hold the
// first 4 columns; on exit they hold the next panel's first 4 (loads guarded).
template<int RR>
__device__ __forceinline__ void panel_f(const double2* __restrict__ LT,
    const double* __restrict__ invd, double2 (&y)[9],
    double2 (&A)[9], double2 (&Bb)[9], double2 (&Cc)[9], double2 (&Dd)[9],
    int n, int lane){
  int cb = RR*64;
  int ncol = min(64, n - cb);           // 64, or 8 for RR=8/n=520 (multiple of 4)
  for (int k = 0; k < ncol; k += 4){
    int c = cb + k;
    pf1<RR>(y, A,  invd[c+0], (c+0) & 63, lane); ldcol_f(LT, c+4, n, lane, A);
    pf1<RR>(y, Bb, invd[c+1], (c+1) & 63, lane); ldcol_f(LT, c+5, n, lane, Bb);
    pf1<RR>(y, Cc, invd[c+2], (c+2) & 63, lane); ldcol_f(LT, c+6, n, lane, Cc);
    pf1<RR>(y, Dd, invd[c+3], (c+3) & 63, lane); ldcol_f(LT, c+7, n, lane, Dd);
  }
}

// backward panel RR: columns RR*64+ncol-1 down to RR*64; A,B,C,D hold the top
// 4 columns on entry; exit holds the next-lower panel's top 4 (guarded).
template<int RR>
__device__ __forceinline__ void panel_b(const double2* __restrict__ RZ,
    const double* __restrict__ invd, double2 (&y)[9],
    double2 (&A)[9], double2 (&Bb)[9], double2 (&Cc)[9], double2 (&Dd)[9],
    int n, int lane){
  int cb = RR*64;
  int ncol = min(64, n - cb);
  int ce = cb + ncol - 1;
  for (int k = 0; k < ncol; k += 4){
    int c = ce - k;
    pb1<RR>(y, A,  invd[c-0], (c-0) & 63, lane); ldcol_b(RZ, c-4, lane, A);
    pb1<RR>(y, Bb, invd[c-1], (c-1) & 63, lane); ldcol_b(RZ, c-5, lane, Bb);
    pb1<RR>(y, Cc, invd[c-2], (c-2) & 63, lane); ldcol_b(RZ, c-6, lane, Cc);
    pb1<RR>(y, Dd, invd[c-3], (c-3) & 63, lane); ldcol_b(RZ, c-7, lane, Dd);
  }
}

// forward+backward substitution; 256 blocks x 4 waves, 1 RHS per wave,
// fully independent waves (no LDS, no barriers), 4-deep register prefetch
// (load->use distance ~3 column-steps covers L2 latency), zero-blocks skipped.
__global__ __launch_bounds__(256,1) void k_solve(const double2* __restrict__ LT,
    const double2* __restrict__ RZ, const double* __restrict__ invd,
    double2* B0, double2* B1){
  int tid = threadIdx.x, lane = tid & 63, z = tid >> 6;
  int w = blockIdx.x*4 + z;                 // 0..1023
  int sys = (w >= 512) ? 1 : 0;
  int c0 = sys ? (w - 512) : w;
  int n = sys ? NO : NE;
  double2* B = sys ? B1 : B0;
  double2 y[9];
  #pragma unroll
  for (int r = 0; r < 9; ++r){
    int t = r*64 + lane;
    y[r] = (t < n) ? B[(size_t)t*512 + c0] : make_double2(0,0);
  }
  double2 A[9], Bb[9], Cc[9], Dd[9];

  // ---------- forward ----------
  ldcol_f(LT, 0, n, lane, A);
  ldcol_f(LT, 1, n, lane, Bb);
  ldcol_f(LT, 2, n, lane, Cc);
  ldcol_f(LT, 3, n, lane, Dd);
  panel_f<0>(LT, invd, y, A, Bb, Cc, Dd, n, lane);
  panel_f<1>(LT, invd, y, A, Bb, Cc, Dd, n, lane);
  panel_f<2>(LT, invd, y, A, Bb, Cc, Dd, n, lane);
  panel_f<3>(LT, invd, y, A, Bb, Cc, Dd, n, lane);
  panel_f<4>(LT, invd, y, A, Bb, Cc, Dd, n, lane);
  panel_f<5>(LT, invd, y, A, Bb, Cc, Dd, n, lane);
  panel_f<6>(LT, invd, y, A, Bb, Cc, Dd, n, lane);
  panel_f<7>(LT, invd, y, A, Bb, Cc, Dd, n, lane);
  if (n > 512) panel_f<8>(LT, invd, y, A, Bb, Cc, Dd, n, lane);

  // ---------- backward ----------
  ldcol_b(RZ, n-1, lane, A);
  ldcol_b(RZ, n-2, lane, Bb);
  ldcol_b(RZ, n-3, lane, Cc);
  ldcol_b(RZ, n-4, lane, Dd);
  if (n > 512) panel_b<8>(RZ, invd, y, A, Bb, Cc, Dd, n, lane);
  panel_b<7>(RZ, invd, y, A, Bb, Cc, Dd, n, lane);
  panel_b<6>(RZ, invd, y, A, Bb, Cc, Dd, n, lane);
  panel_b<5>(RZ, invd, y, A, Bb, Cc, Dd, n, lane);
  panel_b<4>(RZ, invd, y, A, Bb, Cc, Dd, n, lane);
  panel_b<3>(RZ, invd, y, A, Bb, Cc, Dd, n, lane);
  panel_b<2>(RZ, invd, y, A, Bb, Cc, Dd, n, lane);
  panel_b<1>(RZ, invd, y, A, Bb, Cc, Dd, n, lane);
  panel_b<0>(RZ, invd, y, A, Bb, Cc, Dd, n, lane);

  #pragma unroll
  for (int r = 0; r < 9; ++r){
    int t = r*64 + lane;
    if (t < n) B[(size_t)t*512 + c0] = y[r];
  }
}

// eta output (interleave even/odd systems, f64 -> f32)
__global__ __launch_bounds__(256) void k_eta(const double2* B0, const double2* B1,
                                             float* out_eta, int cpx){
  int idx = blockIdx.x*256 + threadIdx.x;
  if (idx >= NQ*512) return;
  int q = idx >> 9;
  int m = idx & 511;
  int n = q >> 3, k = q & 7;
  const double2* B = (n & 1) ? B1 : B0;
  int hr = (n >> 1)*8 + k;
  double2 v = B[(size_t)hr*512 + m];
  if (cpx) ((float2*)out_eta)[idx] = make_float2((float)v.x, (float)v.y);
  else     out_eta[idx] = (float)v.x;
}

// fused: b output + g_est output + bsel extraction (BSEL scratch stays complex)
__global__ __launch_bounds__(256) void k_gestb(const double2* B0, const double2* B1,
    const float* psi32, const float* thc32, const float* ths32,
    float* out_b, float* out_g, float2* BSEL, int cpx){
  int m = blockIdx.x; int p = blockIdx.y*256 + threadIdx.x;
  __shared__ float4 eL4[516];
  float2* eL2 = (float2*)eL4;
  for (int e = threadIdx.x; e < NQ; e += 256){
    int n = e >> 3, k = e & 7;
    const double2* B = (n & 1) ? B1 : B0;
    double2 v = B[(size_t)((n >> 1)*8 + k)*512 + m];
    eL2[e] = make_float2((float)v.x, (float)v.y);
  }
  __syncthreads();
  float pr[8];
  #pragma unroll
  for (int k = 0; k < 8; ++k) pr[k] = psi32[k*1024+p];
  float aEx=0, aEy=0, aOx=0, aOy=0;
  size_t bbase = (size_t)m*129*1024 + p;
  for (int n = 0; n < 129; ++n){
    float c = thc32[n*1024+p], s = ths32[n*1024+p];
    float4 e0 = eL4[n*4+0], e1 = eL4[n*4+1], e2 = eL4[n*4+2], e3 = eL4[n*4+3];
    float br = e0.x*pr[0] + e0.z*pr[1] + e1.x*pr[2] + e1.z*pr[3]
             + e2.x*pr[4] + e2.z*pr[5] + e3.x*pr[6] + e3.z*pr[7];
    float bi = e0.y*pr[0] + e0.w*pr[1] + e1.y*pr[2] + e1.w*pr[3]
             + e2.y*pr[4] + e2.w*pr[5] + e3.y*pr[6] + e3.w*pr[7];
    if (cpx) ((float2*)out_b)[bbase + (size_t)n*1024] = make_float2(br, bi);
    else     out_b[bbase + (size_t)n*1024] = br;
    if ((p & 127) == 0) BSEL[(size_t)m*NQ + n*8 + (p >> 7)] = make_float2(br, bi);
    float tr = c*br - s*bi, ti = c*bi + s*br;
    if (n & 1){ aOx += tr; aOy += ti; } else { aEx += tr; aEy += ti; }
  }
  if (cpx){
    ((float2*)out_g)[(size_t)m*2048 + p]        = make_float2(aEx+aOx, aEy+aOy);
    ((float2*)out_g)[(size_t)m*2048 + p + 1024] = make_float2(aEx-aOx, aEy-aOy);
  } else {
    out_g[(size_t)m*2048 + p]        = aEx+aOx;
    out_g[(size_t)m*2048 + p + 1024] = aEx-aOx;
  }
}

// f_pol_est_s output
__global__ __launch_bounds__(256) void k_fpol(const float2* BSEL, const float* thc32,
    const float* ths32, float* out_f, int cpx){
  int m = blockIdx.x; int p = blockIdx.y*256 + threadIdx.x;
  __shared__ float4 bs4[516];
  float2* bs2 = (float2*)bs4;
  for (int e = threadIdx.x; e < NQ; e += 256) bs2[e] = BSEL[(size_t)m*NQ + e];
  __syncthreads();
  float ar[8] = {0,0,0,0,0,0,0,0}, ai[8] = {0,0,0,0,0,0,0,0};
  for (int n = 0; n < 129; ++n){
    float c = thc32[n*1024+p], s = ths32[n*1024+p];
    #pragma unroll
    for (int jj = 0; jj < 4; ++jj){
      float4 v = bs4[n*4+jj];
      ar[2*jj]   += c*v.x - s*v.y;  ai[2*jj]   += c*v.y + s*v.x;
      ar[2*jj+1] += c*v.z - s*v.w;  ai[2*jj+1] += c*v.w + s*v.z;
    }
  }
  if (cpx){
    float4* o = (float4*)(out_f + ((size_t)m*1024 + p)*16);
    o[0] = make_float4(ar[0],ai[0],ar[1],ai[1]);
    o[1] = make_float4(ar[2],ai[2],ar[3],ai[3]);
    o[2] = make_float4(ar[4],ai[4],ar[5],ai[5]);
    o[3] = make_float4(ar[6],ai[6],ar[7],ai[7]);
  } else {
    float4* o = (float4*)(out_f + ((size_t)m*1024 + p)*8);
    o[0] = make_float4(ar[0],ar[1],ar[2],ar[3]);
    o[1] = make_float4(ar[4],ar[5],ar[6],ar[7]);
  }
}

extern "C" void kernel_launch(void* const* d_in, const int* in_sizes, int n_in,
                              void* d_out, int out_size, void* d_ws, size_t ws_size,
                              hipStream_t stream){
  const float* g     = (const float*)d_in[0];
  const float* tf    = (const float*)d_in[1];
  const float* theta = (const float*)d_in[2];
  float* out = (float*)d_out;

  int cpx = (out_size >= C_TOTAL) ? 1 : 0;
  float* o_eta = out + (cpx ? C_ETA : R_ETA);
  float* o_l1  = out + (cpx ? C_L1  : R_L1);
  float* o_g   = out + (cpx ? C_G   : R_G);
  float* o_b   = out + (cpx ? C_B   : R_B);
  float* o_f   = out + (cpx ? C_F   : R_F);
  float* o_psi = out + (cpx ? C_PSI : R_PSI);

  // scratch pools: prefer d_ws when large enough, else carve from late-written outputs
  size_t need = (size_t)SB_TOTAL + (size_t)SL_TOTALF*4 + 4096;
  char*  sb;     // fp64 pool base
  float* sl;     // fp32 pool base
  if (ws_size >= need){
    sb = (char*)d_ws;
    sl = (float*)((char*)d_ws + SB_TOTAL);
  } else {
    sb = (char*)o_b;   // o_b region: >=270 MB (real) / 541 MB (cpx), dead until k_gestb
    sl = o_l1;         // o_l1 region: >=2.1M floats, dead until k_l1out (runs last)
  }
  float*   psi32 = sl + SL_PSI32;
  float*   thc32 = sl + SL_THC32;
  float*   ths32 = sl + SL_THS32;
  float2*  BSEL  = (float2*)(sl + SL_BSEL);
  double*  psi64 = (double*)(sb + SB_PSI64);
  double*  thc64 = (double*)(sb + SB_THC64);
  double*  ths64 = (double*)(sb + SB_THS64);
  double2* Ct    = (double2*)(sb + SB_CT);
  double2* A0    = (double2*)(sb + SB_A0);
  double2* B0    = (double2*)(sb + SB_B0);
  double2* B1    = (double2*)(sb + SB_B1);
  double*  INVD  = (double*)(sb + SB_INVD);
  double2* LT    = (double2*)(sb + SB_LT);
  double2* RZ    = (double2*)(sb + SB_RZ);

  k_prep <<<548, 256, 0, stream>>>(tf, theta, psi32, psi64, thc64, ths64, thc32, ths32, o_psi, cpx);
  k_ctab <<<65, 256, 0, stream>>>(theta, psi64, Ct);
  k_afill<<<1057, 256, 0, stream>>>(Ct, A0);
  k_bgemm<<<dim3(129,4), 256, 0, stream>>>(g, thc64, ths64, psi64, B0, B1);
  for (int s = 0; s < 8; ++s){
    k_potrf<<<1, 256, 0, stream>>>(A0, INVD, s*65);
    int rem = NE - 65*(s+1);
    if (rem > 0){
      k_trsm<<<(rem+3)/4, 256, 0, stream>>>(A0, INVD, s*65);
      int nt = (rem+31)/32;
      k_syrk<<<dim3(nt,nt), 256, 0, stream>>>(A0, s*65);
    }
  }
  k_tr   <<<dim3(17,18), 256, 0, stream>>>(A0, LT);
  k_rz   <<<(NE*576 + 255)/256, 256, 0, stream>>>(A0, RZ);
  k_solve<<<256, 256, 0, stream>>>(LT, RZ, INVD, B0, B1);
  k_eta  <<<2064, 256, 0, stream>>>(B0, B1, o_eta, cpx);
  k_gestb<<<dim3(512,4), 256, 0, stream>>>(B0, B1, psi32, thc32, ths32, o_b, o_g, BSEL, cpx);
  k_fpol <<<dim3(512,4), 256, 0, stream>>>(BSEL, thc32, ths32, o_f, cpx);
  k_l1out<<<2048, 256, 0, stream>>>(tf, theta, o_l1, cpx);
}